// Round 2
// baseline (198.049 us; speedup 1.0000x reference)
//
#include <hip/hip_runtime.h>

#define NDIMS 3
#define H_HALF 256
#define F_DIM 16
#define PI_F 3.14159265358979323846f

// ---------------------------------------------------------------------------
// Kernel A: conditionals c[n,f] = 1 / trapz(relu(y(t)), t), t=linspace(0.01,1,100)
// y(t) = 1 + 2*sum_{j=1..H} [cos(2pi j t) fr[n,H-j,f] - sin(2pi j t) fi[n,H-j,f]]
// One block per (n,f), 64 threads split the 100 t-samples.
// ---------------------------------------------------------------------------
__global__ __launch_bounds__(64) void cond_kernel(const float* __restrict__ fr,
                                                  const float* __restrict__ fi,
                                                  float* __restrict__ c_out) {
    const int n = blockIdx.x / F_DIM;
    const int f = blockIdx.x % F_DIM;
    const int lane = threadIdx.x;
    const float dt = 0.01f;
    float sum = 0.f;
    for (int ti = lane; ti < 100; ti += 64) {
        float t = 0.01f + dt * (float)ti;
        float beta = 2.f * PI_F * t;
        float cb = __cosf(beta);   // NOTE: explicit cos/sin — __sincosf arg order is (sin, cos)!
        float sb = __sinf(beta);
        float cj = cb, sj = sb;    // cos/sin(2pi*1*t)
        float acc = 0.f;
        for (int j = 1; j <= H_HALF; ++j) {
            int h = H_HALF - j;
            float a = fr[(n * H_HALF + h) * F_DIM + f];
            float b = fi[(n * H_HALF + h) * F_DIM + f];
            acc += cj * a - sj * b;
            float cn = cj * cb - sj * sb;   // angle addition: advance by beta
            float sn = sj * cb + cj * sb;
            cj = cn; sj = sn;
        }
        float y = fmaxf(fmaf(2.f, acc, 1.f), 0.f);
        float w = (ti == 0 || ti == 99) ? 0.5f * dt : dt;  // trapz weights
        sum += w * y;
    }
    // wave64 reduction
    #pragma unroll
    for (int off = 32; off > 0; off >>= 1)
        sum += __shfl_down(sum, off, 64);
    if (lane == 0) c_out[n * F_DIM + f] = 1.f / sum;
}

// ---------------------------------------------------------------------------
// Kernel B: out[m] = sum_f lam[f] * prod_n relu(proj[n,m,f]) * c[n,f]
// proj via the symmetric half-sum; sin/cos by angle-addition recurrence.
// One thread per sample m. Factor reads are wave-uniform -> expect s_load.
// ---------------------------------------------------------------------------
__global__ __launch_bounds__(256) void main_kernel(const float* __restrict__ x,
                                                   const float* __restrict__ fr,
                                                   const float* __restrict__ fi,
                                                   const float* __restrict__ lam,
                                                   const float* __restrict__ c_cond,
                                                   float* __restrict__ out,
                                                   int M) {
    const int m = blockIdx.x * blockDim.x + threadIdx.x;
    if (m >= M) return;

    float res[F_DIM];
    #pragma unroll
    for (int f = 0; f < F_DIM; ++f) res[f] = 1.f;

    #pragma unroll
    for (int n = 0; n < NDIMS; ++n) {
        float xv = x[m * NDIMS + n];
        float beta = 2.f * PI_F * xv;
        float cb = __cosf(beta);   // explicit — do not use __sincosf (arg order trap)
        float sb = __sinf(beta);
        float cj = cb, sj = sb;    // cos/sin(2pi*1*x)

        float acc[F_DIM];
        #pragma unroll
        for (int f = 0; f < F_DIM; ++f) acc[f] = 0.f;

        const float* frn = fr + n * H_HALF * F_DIM;
        const float* fin = fi + n * H_HALF * F_DIM;

        #pragma unroll 2
        for (int j = 1; j <= H_HALF; ++j) {
            const int h = H_HALF - j;
            #pragma unroll
            for (int f = 0; f < F_DIM; ++f) {
                // acc[f] += cj*fr - sj*fi  (2 FMAs)
                acc[f] = fmaf(cj, frn[h * F_DIM + f], acc[f]);
                acc[f] = fmaf(-sj, fin[h * F_DIM + f], acc[f]);
            }
            float cn = cj * cb - sj * sb;
            float sn = sj * cb + cj * sb;
            cj = cn; sj = sn;
        }

        #pragma unroll
        for (int f = 0; f < F_DIM; ++f) {
            float p = fmaxf(fmaf(2.f, acc[f], 1.f), 0.f) * c_cond[n * F_DIM + f];
            res[f] *= p;
        }
    }

    float o = 0.f;
    #pragma unroll
    for (int f = 0; f < F_DIM; ++f) o = fmaf(res[f], lam[f], o);
    out[m] = o;
}

extern "C" void kernel_launch(void* const* d_in, const int* in_sizes, int n_in,
                              void* d_out, int out_size, void* d_ws, size_t ws_size,
                              hipStream_t stream) {
    const float* x   = (const float*)d_in[0];   // (M, 3)
    const float* fr  = (const float*)d_in[1];   // (3, 256, 16)
    const float* fi  = (const float*)d_in[2];   // (3, 256, 16)
    const float* lam = (const float*)d_in[3];   // (16,)
    float* out = (float*)d_out;                 // (M,)
    float* c_ws = (float*)d_ws;                 // 48 floats: c[n,f]

    const int M = in_sizes[0] / NDIMS;

    cond_kernel<<<NDIMS * F_DIM, 64, 0, stream>>>(fr, fi, c_ws);
    main_kernel<<<(M + 255) / 256, 256, 0, stream>>>(x, fr, fi, lam, c_ws, out, M);
}

// Round 3
// 114.585 us; speedup vs baseline: 1.7284x; 1.7284x over previous
//
#include <hip/hip_runtime.h>

#define NDIMS 3
#define H_HALF 256
#define F_DIM 16
#define PI_F 3.14159265358979323846f
#define JSPLIT 4
#define JCHUNK 64   // H_HALF / JSPLIT

// ---------------------------------------------------------------------------
// cond_partial: partial trapz integrals. Grid = 3 n * 7 t-chunks.
// Lanes = (t-sample quarter, f): factor loads are per-lane coalesced vector
// loads (f contiguous), deep vmcnt pipelining hides latency.
// part_out[(n*7+chunk)*16 + f] = sum over this chunk's 16 t-samples of w(t)*relu(y)
// ---------------------------------------------------------------------------
__global__ __launch_bounds__(256) void cond_partial_kernel(const float* __restrict__ fr,
                                                           const float* __restrict__ fi,
                                                           float* __restrict__ part_out) {
    const int n = blockIdx.x / 7;
    const int chunk = blockIdx.x % 7;
    const int tid = threadIdx.x;
    const int f = tid & 15;
    const int tq = tid >> 4;            // 0..15 within block
    const int t_idx = chunk * 16 + tq;  // 0..111 (valid < 100)
    const float t = 0.01f + 0.01f * (float)t_idx;
    const float beta = 2.f * PI_F * t;
    const float cb = __cosf(beta), sb = __sinf(beta);
    float cj = cb, sj = sb;             // cos/sin(2pi*1*t)
    const float* frn = fr + n * H_HALF * F_DIM + f;
    const float* fin = fi + n * H_HALF * F_DIM + f;
    float acc = 0.f;
    #pragma unroll 8
    for (int j = 1; j <= H_HALF; ++j) {
        const int h = H_HALF - j;
        acc = fmaf(cj, frn[h * F_DIM], acc);
        acc = fmaf(-sj, fin[h * F_DIM], acc);
        const float cn = fmaf(cj, cb, -sj * sb);   // advance angle by beta
        const float sn = fmaf(sj, cb, cj * sb);
        cj = cn; sj = sn;
    }
    const float y = fmaxf(fmaf(2.f, acc, 1.f), 0.f);
    const float wgt = (t_idx == 0 || t_idx == 99) ? 0.005f : 0.01f;  // trapz weights
    float contrib = (t_idx < 100) ? wgt * y : 0.f;
    // reduce over tq within wave (lanes differing in bits 4,5)
    contrib += __shfl_xor(contrib, 16, 64);
    contrib += __shfl_xor(contrib, 32, 64);
    __shared__ float red[4][16];
    const int wv = tid >> 6;
    const int lane = tid & 63;
    if (lane < 16) red[wv][lane] = contrib;  // lanes 0..15 hold f = lane
    __syncthreads();
    if (tid < 16) {
        const float s = red[0][tid] + red[1][tid] + red[2][tid] + red[3][tid];
        part_out[blockIdx.x * 16 + tid] = s;
    }
}

// ---------------------------------------------------------------------------
// cond_finalize: c[n,f] = 1 / sum(partials). 48 values.
// ---------------------------------------------------------------------------
__global__ __launch_bounds__(64) void cond_finalize_kernel(const float* __restrict__ part,
                                                           float* __restrict__ c_out) {
    const int tid = threadIdx.x;
    if (tid < 48) {
        const int n = tid >> 4, f = tid & 15;
        float s = 0.f;
        #pragma unroll
        for (int c = 0; c < 7; ++c) s += part[(n * 7 + c) * 16 + f];
        c_out[tid] = 1.f / s;
    }
}

// ---------------------------------------------------------------------------
// main: block = 4 waves x 64 lanes. lane = m (64 samples per block),
// wave w handles j in [w*64+1, w*64+64]. Partial acc[16] reduced via LDS.
// Phase 2: thread t owns (m_local = t>>2, f-quad = t&3); prod kept in regs
// across the 3 dims; final lam-dot reduced over 4 lanes by shfl_xor.
// ---------------------------------------------------------------------------
__global__ __launch_bounds__(256) void main_kernel(const float* __restrict__ x,
                                                   const float* __restrict__ fr,
                                                   const float* __restrict__ fi,
                                                   const float* __restrict__ lam,
                                                   const float* __restrict__ c_cond,
                                                   float* __restrict__ out) {
    // rows padded to 5 float4 (80 B): 16B-aligned b128, banks spread (stride 20)
    __shared__ float4 part[JSPLIT][64][5];
    const int tid = threadIdx.x;
    const int lane = tid & 63;
    const int w = __builtin_amdgcn_readfirstlane(tid >> 6);  // keep j-chunk uniform -> s_load
    const int m = blockIdx.x * 64 + lane;
    const float xs0 = x[m * 3 + 0];
    const float xs1 = x[m * 3 + 1];
    const float xs2 = x[m * 3 + 2];
    const int ml = tid >> 2;          // phase-2 m_local
    const int f4 = tid & 3;           // phase-2 f-quad
    float4 prod = {1.f, 1.f, 1.f, 1.f};

    #pragma unroll
    for (int n = 0; n < NDIMS; ++n) {
        const float xv = (n == 0) ? xs0 : ((n == 1) ? xs1 : xs2);
        const float beta = 2.f * PI_F * xv;
        const float cb = __cosf(beta), sb = __sinf(beta);
        const int j0 = w * JCHUNK + 1;
        const float u0 = (float)j0 * beta;
        float cj = __cosf(u0), sj = __sinf(u0);   // cos/sin(2pi*j0*x)
        float4 a0 = {0,0,0,0}, a1 = {0,0,0,0}, a2 = {0,0,0,0}, a3 = {0,0,0,0};
        const float4* frn = (const float4*)(fr + n * H_HALF * F_DIM);
        const float4* fin = (const float4*)(fi + n * H_HALF * F_DIM);
        #pragma unroll 4
        for (int i = 0; i < JCHUNK; ++i) {
            const int h = H_HALF - 1 - (w * JCHUNK + i);   // = H - j
            const float4 r0 = frn[h * 4 + 0], r1 = frn[h * 4 + 1];
            const float4 r2 = frn[h * 4 + 2], r3 = frn[h * 4 + 3];
            const float4 q0 = fin[h * 4 + 0], q1 = fin[h * 4 + 1];
            const float4 q2 = fin[h * 4 + 2], q3 = fin[h * 4 + 3];
            a0.x = fmaf(cj, r0.x, a0.x); a0.y = fmaf(cj, r0.y, a0.y);
            a0.z = fmaf(cj, r0.z, a0.z); a0.w = fmaf(cj, r0.w, a0.w);
            a1.x = fmaf(cj, r1.x, a1.x); a1.y = fmaf(cj, r1.y, a1.y);
            a1.z = fmaf(cj, r1.z, a1.z); a1.w = fmaf(cj, r1.w, a1.w);
            a2.x = fmaf(cj, r2.x, a2.x); a2.y = fmaf(cj, r2.y, a2.y);
            a2.z = fmaf(cj, r2.z, a2.z); a2.w = fmaf(cj, r2.w, a2.w);
            a3.x = fmaf(cj, r3.x, a3.x); a3.y = fmaf(cj, r3.y, a3.y);
            a3.z = fmaf(cj, r3.z, a3.z); a3.w = fmaf(cj, r3.w, a3.w);
            a0.x = fmaf(-sj, q0.x, a0.x); a0.y = fmaf(-sj, q0.y, a0.y);
            a0.z = fmaf(-sj, q0.z, a0.z); a0.w = fmaf(-sj, q0.w, a0.w);
            a1.x = fmaf(-sj, q1.x, a1.x); a1.y = fmaf(-sj, q1.y, a1.y);
            a1.z = fmaf(-sj, q1.z, a1.z); a1.w = fmaf(-sj, q1.w, a1.w);
            a2.x = fmaf(-sj, q2.x, a2.x); a2.y = fmaf(-sj, q2.y, a2.y);
            a2.z = fmaf(-sj, q2.z, a2.z); a2.w = fmaf(-sj, q2.w, a2.w);
            a3.x = fmaf(-sj, q3.x, a3.x); a3.y = fmaf(-sj, q3.y, a3.y);
            a3.z = fmaf(-sj, q3.z, a3.z); a3.w = fmaf(-sj, q3.w, a3.w);
            const float cn = fmaf(cj, cb, -sj * sb);
            const float sn = fmaf(sj, cb, cj * sb);
            cj = cn; sj = sn;
        }
        part[w][lane][0] = a0;
        part[w][lane][1] = a1;
        part[w][lane][2] = a2;
        part[w][lane][3] = a3;
        __syncthreads();
        {
            const float4 v0 = part[0][ml][f4];
            const float4 v1 = part[1][ml][f4];
            const float4 v2 = part[2][ml][f4];
            const float4 v3 = part[3][ml][f4];
            float4 s;
            s.x = (v0.x + v1.x) + (v2.x + v3.x);
            s.y = (v0.y + v1.y) + (v2.y + v3.y);
            s.z = (v0.z + v1.z) + (v2.z + v3.z);
            s.w = (v0.w + v1.w) + (v2.w + v3.w);
            const float4 c4 = ((const float4*)c_cond)[n * 4 + f4];
            prod.x *= fmaxf(fmaf(2.f, s.x, 1.f), 0.f) * c4.x;
            prod.y *= fmaxf(fmaf(2.f, s.y, 1.f), 0.f) * c4.y;
            prod.z *= fmaxf(fmaf(2.f, s.z, 1.f), 0.f) * c4.z;
            prod.w *= fmaxf(fmaf(2.f, s.w, 1.f), 0.f) * c4.w;
        }
        __syncthreads();  // protect part[] before next n's writes
    }
    const float4 l4 = ((const float4*)lam)[f4];
    float partial = fmaf(prod.x, l4.x, fmaf(prod.y, l4.y, fmaf(prod.z, l4.z, prod.w * l4.w)));
    partial += __shfl_xor(partial, 1, 64);
    partial += __shfl_xor(partial, 2, 64);
    if ((tid & 3) == 0) out[blockIdx.x * 64 + ml] = partial;
}

extern "C" void kernel_launch(void* const* d_in, const int* in_sizes, int n_in,
                              void* d_out, int out_size, void* d_ws, size_t ws_size,
                              hipStream_t stream) {
    const float* x   = (const float*)d_in[0];   // (M, 3)
    const float* fr  = (const float*)d_in[1];   // (3, 256, 16)
    const float* fi  = (const float*)d_in[2];   // (3, 256, 16)
    const float* lam = (const float*)d_in[3];   // (16,)
    float* out = (float*)d_out;                 // (M,)
    float* part = (float*)d_ws;                 // 3*7*16 = 336 floats
    float* c_ws = (float*)d_ws + 336;           // 48 floats (16B-aligned: 336*4=1344)

    const int M = in_sizes[0] / NDIMS;

    cond_partial_kernel<<<NDIMS * 7, 256, 0, stream>>>(fr, fi, part);
    cond_finalize_kernel<<<1, 64, 0, stream>>>(part, c_ws);
    main_kernel<<<M / 64, 256, 0, stream>>>(x, fr, fi, lam, c_ws, out);
}